// Round 3
// baseline (224.629 us; speedup 1.0000x reference)
//
#include <hip/hip_runtime.h>

// HolographicConv: out = Re(ifft2(fft2(x) * W)), B == C_out == 16 -> pure
// elementwise complex multiply in frequency space per (b,c) image slice.
// 256 images of 256x256 complex64.
//
// Intermediate lives TRANSPOSED: wsT[v*256 + k_u].
//   K1: FFT over u:  x rows coalesced -> LDS tile -> regs -> FFT ->
//       direct coalesced stores to wsT rows (no out tile).
//   K2: FFT over v + mul W + IFFT over v, per 16-k stripe, in-place on wsT.
//       W(k,l) read coalesced straight into registers (no W tile).
//   K3: IFFT over k: wsT rows contiguous -> regs (no in tile) -> FFT ->
//       real transpose tile -> coalesced out writes.
//
// FFT-256 = radix-4 Stockham, 4 stages, one wave per transform, 4 complex
// elems/lane. Each wave runs FOUR interleaved FFTs (ILP-4). The Stockham
// LDS scratch ALIASES the transpose tile (tile is dead during the FFT),
// so every kernel fits 4 blocks/CU (16 waves/CU) instead of 3.

#define PI_F 3.14159265358979323846f

__device__ __forceinline__ float2 cadd(float2 a, float2 b){ return make_float2(a.x+b.x, a.y+b.y); }
__device__ __forceinline__ float2 csub(float2 a, float2 b){ return make_float2(a.x-b.x, a.y-b.y); }
__device__ __forceinline__ float2 cmul(float2 a, float2 b){
  return make_float2(a.x*b.x - a.y*b.y, a.x*b.y + a.y*b.x);
}

// XOR swizzle for the Stockham scratch.
__device__ __forceinline__ int SW(int e){ return e ^ (e >> 4); }

template<int DIR>  // +1: forward e^{-i}, -1: inverse e^{+i} (unnormalized)
__device__ __forceinline__ void bfly4(float2& a, float2& b, float2& c, float2& d,
                                      float2 w1, float2 w2, float2 w3)
{
  float2 apc = cadd(a,c), amc = csub(a,c);
  float2 bpd = cadd(b,d), bmd = csub(b,d);
  float2 jb = (DIR > 0) ? make_float2(-bmd.y, bmd.x)   //  i*(b-d)
                        : make_float2( bmd.y,-bmd.x);  // -i*(b-d)
  a = cadd(apc, bpd);
  b = cmul(w1, csub(amc, jb));
  c = cmul(w2, csub(apc, bpd));
  d = cmul(w3, cadd(amc, jb));
}

// Four interleaved FFT-256s per wave (ILP-4). scr = wave's 4*256 float2
// region (chain c uses scr + c*256). tw[k] = exp(-2*pi*i*k/256).
template<int DIR>
__device__ __forceinline__ void fft256_x4(float2 v[4][4], float2* scr,
                                          const float2* tw, int lane)
{
  #pragma unroll
  for (int st = 0; st < 3; ++st) {               // s = 1, 4, 16
    const int s  = 1 << (2*st);
    const int ps = lane & ~(s-1);                // p*s
    const int q  = lane &  (s-1);
    float2 w1 = tw[ps];
    float2 w2 = tw[(2*ps) & 255];
    float2 w3 = tw[(3*ps) & 255];
    if (DIR < 0) { w1.y = -w1.y; w2.y = -w2.y; w3.y = -w3.y; }
    #pragma unroll
    for (int c = 0; c < 4; ++c)
      bfly4<DIR>(v[c][0], v[c][1], v[c][2], v[c][3], w1, w2, w3);
    const int dbase = q + 4*ps;                  // q + s*4p
    __builtin_amdgcn_wave_barrier();
    #pragma unroll
    for (int c = 0; c < 4; ++c) {
      float2* s_ = scr + c*256;
      s_[SW(dbase + 0*s)] = v[c][0];
      s_[SW(dbase + 1*s)] = v[c][1];
      s_[SW(dbase + 2*s)] = v[c][2];
      s_[SW(dbase + 3*s)] = v[c][3];
    }
    __builtin_amdgcn_wave_barrier();             // in-order LDS per wave -> safe
    #pragma unroll
    for (int c = 0; c < 4; ++c) {
      float2* s_ = scr + c*256;
      v[c][0] = s_[SW(lane +   0)];
      v[c][1] = s_[SW(lane +  64)];
      v[c][2] = s_[SW(lane + 128)];
      v[c][3] = s_[SW(lane + 192)];
    }
    __builtin_amdgcn_wave_barrier();
  }
  const float2 one = make_float2(1.f, 0.f);      // s=64 stage: unit twiddles
  #pragma unroll
  for (int c = 0; c < 4; ++c)
    bfly4<DIR>(v[c][0], v[c][1], v[c][2], v[c][3], one, one, one);
}

__device__ __forceinline__ void init_tw(float2* tw, int tid)
{
  float sv, cv;
  sincosf(-2.0f * PI_F * (float)tid / 256.0f, &sv, &cv);
  tw[tid] = make_float2(cv, sv);
}

// ---------------- K1: FFT over u, write wsT[v][k] --------------------------
__global__ __launch_bounds__(256, 4) void k_colfft(const float* __restrict__ xr,
                                                   const float* __restrict__ xi,
                                                   float2* __restrict__ wsT)
{
  __shared__ float2 pool[4352];    // tile [256][17]; scr aliases [0..4096)
  __shared__ float2 tw[256];
  const int tid = threadIdx.x;
  init_tw(tw, tid);
  const int imgl = blockIdx.x >> 4;
  const int v0   = (blockIdx.x & 15) * 16;
  const size_t ib = (size_t)imgl * 65536;
  const int c  = tid & 15;
  const int h0 = tid >> 4;
  #pragma unroll
  for (int t = 0; t < 16; ++t) {
    const int u = t*16 + h0;
    pool[u*17 + c] = make_float2(xr[ib + (size_t)u*256 + v0 + c],
                                 xi[ib + (size_t)u*256 + v0 + c]);
  }
  __syncthreads();
  const int wave = tid >> 6, lane = tid & 63;
  float2 v[4][4];
  #pragma unroll
  for (int cq = 0; cq < 4; ++cq)
    #pragma unroll
    for (int r = 0; r < 4; ++r)
      v[cq][r] = pool[(lane + 64*r)*17 + wave*4 + cq];
  __syncthreads();                 // all tile reads done before scr overwrite
  fft256_x4<1>(v, pool + wave*1024, tw, lane);
  #pragma unroll
  for (int cq = 0; cq < 4; ++cq) {
    float2* o = wsT + ib + (size_t)(v0 + wave*4 + cq)*256;
    #pragma unroll
    for (int r = 0; r < 4; ++r) o[lane + 64*r] = v[cq][r];
  }
}

// ---------------- K2: FFT over v, * W, IFFT over v (in-place on wsT) -------
__global__ __launch_bounds__(256, 4) void k_rowpass(float2* __restrict__ wsT,
                                                    const float* __restrict__ wr,
                                                    const float* __restrict__ wi,
                                                    int img0)
{
  __shared__ float2 pool[4352];    // tile [256][17]; scr aliases [0..4096)
  __shared__ float2 tw[256];
  const int tid = threadIdx.x;
  init_tw(tw, tid);
  const int imgl = blockIdx.x >> 4;
  const int k0   = (blockIdx.x & 15) * 16;
  const size_t ib = (size_t)imgl * 65536;
  const size_t wb = (size_t)(img0 + imgl) * 65536;
  const int c  = tid & 15;
  const int h0 = tid >> 4;
  #pragma unroll
  for (int t = 0; t < 16; ++t) {
    const int vv = t*16 + h0;
    pool[vv*17 + c] = wsT[ib + (size_t)vv*256 + k0 + c];
  }
  __syncthreads();
  const int wave = tid >> 6, lane = tid & 63;
  float2 v[4][4];
  #pragma unroll
  for (int cq = 0; cq < 4; ++cq)
    #pragma unroll
    for (int r = 0; r < 4; ++r)
      v[cq][r] = pool[(lane + 64*r)*17 + wave*4 + cq];
  __syncthreads();                 // all tile reads done before scr overwrite
  // W prefetch AFTER the barrier (hipcc drains vmcnt at s_barrier): the
  // ~900cy HBM latency hides under the forward FFT below.
  float2 wv[4][4];
  #pragma unroll
  for (int cq = 0; cq < 4; ++cq) {
    const size_t base = wb + (size_t)(k0 + wave*4 + cq)*256;
    #pragma unroll
    for (int r = 0; r < 4; ++r) {
      const int l = lane + 64*r;
      wv[cq][r] = make_float2(wr[base + l], wi[base + l]);
    }
  }
  fft256_x4<1>(v, pool + wave*1024, tw, lane);
  #pragma unroll
  for (int cq = 0; cq < 4; ++cq)
    #pragma unroll
    for (int r = 0; r < 4; ++r)
      v[cq][r] = cmul(v[cq][r], wv[cq][r]);
  fft256_x4<-1>(v, pool + wave*1024, tw, lane);
  __syncthreads();                 // everyone done with scr
  #pragma unroll
  for (int cq = 0; cq < 4; ++cq)
    #pragma unroll
    for (int r = 0; r < 4; ++r)
      pool[(lane + 64*r)*17 + wave*4 + cq] = v[cq][r];
  __syncthreads();
  #pragma unroll
  for (int t = 0; t < 16; ++t) {
    const int vv = t*16 + h0;
    wsT[ib + (size_t)vv*256 + k0 + c] = pool[vv*17 + c];
  }
}

// ---------------- K3: IFFT over k, write Re/65536 (transposed out) ---------
__global__ __launch_bounds__(256, 4) void k_rowifft(const float2* __restrict__ wsT,
                                                    float* __restrict__ out)
{
  __shared__ float2 pool[4096];    // scr; real out tile [256][17] aliases it
  __shared__ float2 tw[256];
  const int tid = threadIdx.x;
  init_tw(tw, tid);
  const int imgl = blockIdx.x >> 4;
  const int v0   = (blockIdx.x & 15) * 16;
  const size_t ib = (size_t)imgl * 65536;
  const int wave = tid >> 6, lane = tid & 63;
  float2 v[4][4];
  #pragma unroll
  for (int cq = 0; cq < 4; ++cq) {
    const float2* p = wsT + ib + (size_t)(v0 + wave*4 + cq)*256;
    #pragma unroll
    for (int r = 0; r < 4; ++r) v[cq][r] = p[lane + 64*r];
  }
  __syncthreads();                 // tw ready
  fft256_x4<-1>(v, pool + wave*1024, tw, lane);
  __syncthreads();                 // everyone done with scr
  float* ot = (float*)pool;        // [256][17] real
  const float sc = 1.0f / 65536.0f;
  #pragma unroll
  for (int cq = 0; cq < 4; ++cq)
    #pragma unroll
    for (int r = 0; r < 4; ++r)
      ot[(lane + 64*r)*17 + wave*4 + cq] = v[cq][r].x * sc;
  __syncthreads();
  const int c  = tid & 15;
  const int h0 = tid >> 4;
  #pragma unroll
  for (int t = 0; t < 16; ++t) {
    const int u = t*16 + h0;
    out[ib + (size_t)u*256 + v0 + c] = ot[u*17 + c];
  }
}

extern "C" void kernel_launch(void* const* d_in, const int* in_sizes, int n_in,
                              void* d_out, int out_size, void* d_ws, size_t ws_size,
                              hipStream_t stream)
{
  const float* xr = (const float*)d_in[0];
  const float* xi = (const float*)d_in[1];
  const float* wr = (const float*)d_in[2];
  const float* wi = (const float*)d_in[3];
  float* out = (float*)d_out;

  const int IMG = 256;                                    // B * C_IN
  const size_t per_img = (size_t)65536 * sizeof(float2);  // 512 KiB
  int ipc = (int)(ws_size / per_img);                     // images per chunk
  if (ipc < 1)   ipc = 1;
  if (ipc > IMG) ipc = IMG;
  float2* wsp = (float2*)d_ws;

  for (int img0 = 0; img0 < IMG; img0 += ipc) {
    const int n = (IMG - img0 < ipc) ? (IMG - img0) : ipc;
    k_colfft <<<dim3(n*16), dim3(256), 0, stream>>>(xr + (size_t)img0*65536,
                                                    xi + (size_t)img0*65536, wsp);
    k_rowpass<<<dim3(n*16), dim3(256), 0, stream>>>(wsp, wr, wi, img0);
    k_rowifft<<<dim3(n*16), dim3(256), 0, stream>>>(wsp, out + (size_t)img0*65536);
  }
}

// Round 4
// 180.024 us; speedup vs baseline: 1.2478x; 1.2478x over previous
//
#include <hip/hip_runtime.h>

// HolographicConv: out = Re(ifft2(fft2(x) * W)), B == C_out == 16 -> pure
// elementwise complex multiply in frequency space per (b,c) image slice.
// 256 images of 256x256 complex64.
//
// Intermediate TRANSPOSED: wsT[v*256 + k_u].
//   K1: FFT over u.  K2: FFT over v + mul W + IFFT over v (in-place).
//   K3: IFFT over u, write Re/65536.
//
// FFT-256 = radix-4 Stockham, 4 stages, one wave per transform. This round:
// PAIR-VECTORIZED — two adjacent columns ride in one float4
// (A.re,A.im,B.re,B.im), so every LDS access (Stockham scratch AND transpose
// tiles) is b128, halving LDS instruction count (the measured bottleneck).
// Twiddles live in registers (3x sincos, w2=w1^2, w3=w1*w2) — no LDS table.
// Scratch aliases the tile (tile is read to regs up front) -> 36.8KB LDS ->
// 4 blocks/CU. ILP-2 (both pairs held in regs) keeps VGPR ~105 < 128 cap.

#define PI_F 3.14159265358979323846f

__device__ __forceinline__ float2 cmul2(float2 a, float2 b){
  return make_float2(a.x*b.x - a.y*b.y, a.x*b.y + a.y*b.x);
}
__device__ __forceinline__ float4 f4add(float4 a, float4 b){
  return make_float4(a.x+b.x, a.y+b.y, a.z+b.z, a.w+b.w);
}
__device__ __forceinline__ float4 f4sub(float4 a, float4 b){
  return make_float4(a.x-b.x, a.y-b.y, a.z-b.z, a.w-b.w);
}
__device__ __forceinline__ float4 mulI (float4 t){ return make_float4(-t.y, t.x, -t.w, t.z); }
__device__ __forceinline__ float4 mulmI(float4 t){ return make_float4( t.y,-t.x,  t.w,-t.z); }
// both packed complexes times the same scalar complex w
__device__ __forceinline__ float4 cmul_pw(float4 a, float2 w){
  return make_float4(a.x*w.x - a.y*w.y, a.x*w.y + a.y*w.x,
                     a.z*w.x - a.w*w.y, a.z*w.y + a.w*w.x);
}
// per-half complex multiply: (a1*w1, a2*w2) with w packed like a
__device__ __forceinline__ float4 cmul_p4(float4 a, float4 w){
  return make_float4(a.x*w.x - a.y*w.y, a.x*w.y + a.y*w.x,
                     a.z*w.z - a.w*w.w, a.z*w.w + a.w*w.z);
}

// XOR swizzle for the Stockham scratch (float4 cells).
__device__ __forceinline__ int SW(int e){ return e ^ (e >> 4); }

template<int DIR>  // +1: forward e^{-i}, -1: inverse e^{+i} (unnormalized)
__device__ __forceinline__ void bfly4p(float4 v[4], float2 w1, float2 w2, float2 w3)
{
  float4 apc = f4add(v[0], v[2]), amc = f4sub(v[0], v[2]);
  float4 bpd = f4add(v[1], v[3]), bmd = f4sub(v[1], v[3]);
  float4 jb  = (DIR > 0) ? mulI(bmd) : mulmI(bmd);
  v[0] = f4add(apc, bpd);
  v[1] = cmul_pw(f4sub(amc, jb), w1);
  v[2] = cmul_pw(f4sub(apc, bpd), w2);
  v[3] = cmul_pw(f4add(amc, jb), w3);
}

// One FFT-256 over a column-PAIR packed in float4. scr = wave-private
// 256-entry float4 region. tws[st] = {w1,w2,w3} for stages s=1,4,16 (fwd).
template<int DIR>
__device__ __forceinline__ void fft256_p(float4 v[4], float4* scr,
                                         const float2 (&tws)[3][3], int lane)
{
  #pragma unroll
  for (int st = 0; st < 3; ++st) {               // s = 1, 4, 16
    const int s  = 1 << (2*st);
    const int ps = lane & ~(s-1);
    const int q  = lane &  (s-1);
    float2 w1 = tws[st][0], w2 = tws[st][1], w3 = tws[st][2];
    if (DIR < 0) { w1.y = -w1.y; w2.y = -w2.y; w3.y = -w3.y; }
    bfly4p<DIR>(v, w1, w2, w3);
    const int dbase = q + 4*ps;
    __builtin_amdgcn_wave_barrier();
    scr[SW(dbase + 0*s)] = v[0];
    scr[SW(dbase + 1*s)] = v[1];
    scr[SW(dbase + 2*s)] = v[2];
    scr[SW(dbase + 3*s)] = v[3];
    __builtin_amdgcn_wave_barrier();             // in-order LDS per wave
    v[0] = scr[SW(lane +   0)];
    v[1] = scr[SW(lane +  64)];
    v[2] = scr[SW(lane + 128)];
    v[3] = scr[SW(lane + 192)];
    __builtin_amdgcn_wave_barrier();
  }
  bfly4p<DIR>(v, make_float2(1.f,0.f), make_float2(1.f,0.f), make_float2(1.f,0.f));
}

// Per-lane register twiddles: tw[k]=exp(-2*pi*i*k/256); w1=tw[ps], w2=w1^2, w3=w1*w2.
__device__ __forceinline__ void make_tws(float2 (&tws)[3][3], int lane)
{
  #pragma unroll
  for (int st = 0; st < 3; ++st) {
    const int s  = 1 << (2*st);
    const int ps = lane & ~(s-1);
    float sv, cv;
    sincosf(-2.0f * PI_F * (float)ps / 256.0f, &sv, &cv);
    float2 w1 = make_float2(cv, sv);
    float2 w2 = cmul2(w1, w1);
    float2 w3 = cmul2(w1, w2);
    tws[st][0] = w1; tws[st][1] = w2; tws[st][2] = w3;
  }
}

// ---------------- K1: FFT over u, write wsT[v][k_u] ------------------------
__global__ __launch_bounds__(256, 4) void k_colfft(const float* __restrict__ xr,
                                                   const float* __restrict__ xi,
                                                   float2* __restrict__ wsT)
{
  __shared__ float4 pool[2304];        // tile [256][9] f4-pairs; scr aliases [0,1024)
  const int tid  = threadIdx.x;
  const int imgl = blockIdx.x >> 4;
  const int v0   = (blockIdx.x & 15) * 16;
  const size_t ib = (size_t)imgl * 65536;
  const int q  = tid & 3;              // float4 group of 4 v-cols
  const int h0 = tid >> 2;             // 0..63
  #pragma unroll
  for (int t = 0; t < 4; ++t) {
    const int u = h0 + 64*t;
    float4 r4 = *(const float4*)(xr + ib + (size_t)u*256 + v0 + 4*q);
    float4 i4 = *(const float4*)(xi + ib + (size_t)u*256 + v0 + 4*q);
    pool[u*9 + 2*q    ] = make_float4(r4.x, i4.x, r4.y, i4.y);
    pool[u*9 + 2*q + 1] = make_float4(r4.z, i4.z, r4.w, i4.w);
  }
  const int wave = tid >> 6, lane = tid & 63;
  float2 tws[3][3];
  make_tws(tws, lane);
  __syncthreads();
  const int cp1 = wave*2, cp2 = wave*2 + 1;
  float4 v1[4], v2[4];
  #pragma unroll
  for (int r = 0; r < 4; ++r) { v1[r] = pool[(lane + 64*r)*9 + cp1];
                                v2[r] = pool[(lane + 64*r)*9 + cp2]; }
  __syncthreads();                     // tile reads done before scr clobber
  float4* scr = pool + wave*256;
  fft256_p<1>(v1, scr, tws, lane);
  fft256_p<1>(v2, scr, tws, lane);
  {
    float2* oA = wsT + ib + (size_t)(v0 + 2*cp1)*256;
    float2* oB = oA + 256;
    #pragma unroll
    for (int r = 0; r < 4; ++r) {
      const int l = lane + 64*r;
      oA[l] = make_float2(v1[r].x, v1[r].y);
      oB[l] = make_float2(v1[r].z, v1[r].w);
    }
  }
  {
    float2* oA = wsT + ib + (size_t)(v0 + 2*cp2)*256;
    float2* oB = oA + 256;
    #pragma unroll
    for (int r = 0; r < 4; ++r) {
      const int l = lane + 64*r;
      oA[l] = make_float2(v2[r].x, v2[r].y);
      oB[l] = make_float2(v2[r].z, v2[r].w);
    }
  }
}

// ---------------- K2: FFT over v, * W, IFFT over v (in-place on wsT) -------
__global__ __launch_bounds__(256, 4) void k_rowpass(float2* __restrict__ wsT,
                                                    const float* __restrict__ wr,
                                                    const float* __restrict__ wi,
                                                    int img0)
{
  __shared__ float4 pool[2304];        // tile [256][9] f4-pairs; scr aliases [0,1024)
  const int tid  = threadIdx.x;
  const int imgl = blockIdx.x >> 4;
  const int k0   = (blockIdx.x & 15) * 16;
  const size_t ib = (size_t)imgl * 65536;
  const size_t wb = (size_t)(img0 + imgl) * 65536;
  const int c8 = tid & 7;              // f4-pair index within stripe
  const int h0 = tid >> 3;             // 0..31
  #pragma unroll
  for (int t = 0; t < 8; ++t) {
    const int v = h0 + 32*t;
    pool[v*9 + c8] = *(const float4*)(wsT + ib + (size_t)v*256 + k0 + 2*c8);
  }
  const int wave = tid >> 6, lane = tid & 63;
  float2 tws[3][3];
  make_tws(tws, lane);
  __syncthreads();
  const int cp1 = wave*2, cp2 = wave*2 + 1;
  float4 v1[4], v2[4];
  #pragma unroll
  for (int r = 0; r < 4; ++r) { v1[r] = pool[(lane + 64*r)*9 + cp1];
                                v2[r] = pool[(lane + 64*r)*9 + cp2]; }
  __syncthreads();                     // tile reads done before scr clobber
  float4* scr = pool + wave*256;
  // ---- pair 1 ----
  {
    const size_t bA = wb + (size_t)(k0 + 2*cp1)*256, bB = bA + 256;
    float4 wv[4];
    #pragma unroll
    for (int r = 0; r < 4; ++r) {
      const int l = lane + 64*r;
      wv[r] = make_float4(wr[bA + l], wi[bA + l], wr[bB + l], wi[bB + l]);
    }
    fft256_p<1>(v1, scr, tws, lane);
    #pragma unroll
    for (int r = 0; r < 4; ++r) v1[r] = cmul_p4(v1[r], wv[r]);
    fft256_p<-1>(v1, scr, tws, lane);
  }
  // ---- pair 2 ----
  {
    const size_t bA = wb + (size_t)(k0 + 2*cp2)*256, bB = bA + 256;
    float4 wv[4];
    #pragma unroll
    for (int r = 0; r < 4; ++r) {
      const int l = lane + 64*r;
      wv[r] = make_float4(wr[bA + l], wi[bA + l], wr[bB + l], wi[bB + l]);
    }
    fft256_p<1>(v2, scr, tws, lane);
    #pragma unroll
    for (int r = 0; r < 4; ++r) v2[r] = cmul_p4(v2[r], wv[r]);
    fft256_p<-1>(v2, scr, tws, lane);
  }
  __syncthreads();                     // all waves done with scr
  #pragma unroll
  for (int r = 0; r < 4; ++r) { pool[(lane + 64*r)*9 + cp1] = v1[r];
                                pool[(lane + 64*r)*9 + cp2] = v2[r]; }
  __syncthreads();
  #pragma unroll
  for (int t = 0; t < 8; ++t) {
    const int v = h0 + 32*t;
    *(float4*)(wsT + ib + (size_t)v*256 + k0 + 2*c8) = pool[v*9 + c8];
  }
}

// ---------------- K3: IFFT over u, write Re/65536 --------------------------
__global__ __launch_bounds__(256, 6) void k_rowifft(const float2* __restrict__ wsT,
                                                    float* __restrict__ out)
{
  __shared__ float4 pool[1152];        // scr [0,1024); real out tile aliases as f2[2304]
  const int tid  = threadIdx.x;
  const int imgl = blockIdx.x >> 4;
  const int v0   = (blockIdx.x & 15) * 16;
  const size_t ib = (size_t)imgl * 65536;
  const int wave = tid >> 6, lane = tid & 63;
  float2 tws[3][3];
  make_tws(tws, lane);
  float4* scr = pool + wave*256;
  float2* ot  = (float2*)pool;         // [256][9] float2 (pairs of out cols)
  const float sc = 1.0f / 65536.0f;
  float2 res[2][4];
  #pragma unroll
  for (int p = 0; p < 2; ++p) {
    const int cp = wave*2 + p;
    const float2* pA = wsT + ib + (size_t)(v0 + 2*cp)*256;
    const float2* pB = pA + 256;
    float4 v[4];
    #pragma unroll
    for (int r = 0; r < 4; ++r) {
      const int l = lane + 64*r;
      float2 a = pA[l], b = pB[l];
      v[r] = make_float4(a.x, a.y, b.x, b.y);
    }
    fft256_p<-1>(v, scr, tws, lane);
    #pragma unroll
    for (int r = 0; r < 4; ++r) res[p][r] = make_float2(v[r].x * sc, v[r].z * sc);
  }
  __syncthreads();                     // all waves done with scr
  #pragma unroll
  for (int p = 0; p < 2; ++p)
    #pragma unroll
    for (int r = 0; r < 4; ++r)
      ot[(lane + 64*r)*9 + wave*2 + p] = res[p][r];
  __syncthreads();
  const int c4 = tid & 3, h0 = tid >> 2;
  #pragma unroll
  for (int t = 0; t < 4; ++t) {
    const int u = h0 + 64*t;
    float2 a = ot[u*9 + 2*c4], b = ot[u*9 + 2*c4 + 1];
    *(float4*)(out + ib + (size_t)u*256 + v0 + 4*c4) = make_float4(a.x, a.y, b.x, b.y);
  }
}

extern "C" void kernel_launch(void* const* d_in, const int* in_sizes, int n_in,
                              void* d_out, int out_size, void* d_ws, size_t ws_size,
                              hipStream_t stream)
{
  const float* xr = (const float*)d_in[0];
  const float* xi = (const float*)d_in[1];
  const float* wr = (const float*)d_in[2];
  const float* wi = (const float*)d_in[3];
  float* out = (float*)d_out;

  const int IMG = 256;                                    // B * C_IN
  const size_t per_img = (size_t)65536 * sizeof(float2);  // 512 KiB
  int ipc = (int)(ws_size / per_img);                     // images per chunk
  if (ipc < 1)   ipc = 1;
  if (ipc > IMG) ipc = IMG;
  float2* wsp = (float2*)d_ws;

  for (int img0 = 0; img0 < IMG; img0 += ipc) {
    const int n = (IMG - img0 < ipc) ? (IMG - img0) : ipc;
    k_colfft <<<dim3(n*16), dim3(256), 0, stream>>>(xr + (size_t)img0*65536,
                                                    xi + (size_t)img0*65536, wsp);
    k_rowpass<<<dim3(n*16), dim3(256), 0, stream>>>(wsp, wr, wi, img0);
    k_rowifft<<<dim3(n*16), dim3(256), 0, stream>>>(wsp, out + (size_t)img0*65536);
  }
}